// Round 7
// baseline (115.084 us; speedup 1.0000x reference)
//
#include <hip/hip_runtime.h>
#include <hip/hip_bf16.h>
#include <stdint.h>

#define ALPHA 0.2f

typedef __attribute__((ext_vector_type(8))) short bf16x8;
typedef __attribute__((ext_vector_type(4))) float f32x4;

__device__ __forceinline__ short f2bf(float f) {
    union { float f; uint32_t u; } c; c.f = f;
    uint32_t u = c.u + 0x7FFF + ((c.u >> 16) & 1);   // round-to-nearest-even
    return (short)(u >> 16);
}

// pack two fp32 -> packed bf16 pair (round-half-up), 3 VALU ops for 2 elems
__device__ __forceinline__ uint32_t pk_bf16(float lo, float hi) {
    union { float f; uint32_t u; } a, b;
    a.f = lo; b.f = hi;
    return __builtin_amdgcn_perm(b.u + 0x8000u, a.u + 0x8000u, 0x07060302u);
}

// ---------------------------------------------------------------------------
// Kernel 0: pack adj into byte-masks (8 ints -> 1 byte per thread). First 64
// blocks also pre-transpose W (fp32 [k][f]) -> WTg (bf16 [f][k]).
// ---------------------------------------------------------------------------
__global__ __launch_bounds__(256) void pack_adj_kernel(
        const int* __restrict__ adj, uint8_t* __restrict__ bytes,
        const float* __restrict__ W, short* __restrict__ WTg) {
    int t = blockIdx.x * 256 + threadIdx.x;            // 524288 threads
    const int4* a4 = reinterpret_cast<const int4*>(adj) + (size_t)t * 2;
    int4 x0 = a4[0], x1 = a4[1];
    uint32_t m = 0;
    m |= (x0.x > 0) ? 1u   : 0u;  m |= (x0.y > 0) ? 2u   : 0u;
    m |= (x0.z > 0) ? 4u   : 0u;  m |= (x0.w > 0) ? 8u   : 0u;
    m |= (x1.x > 0) ? 16u  : 0u;  m |= (x1.y > 0) ? 32u  : 0u;
    m |= (x1.z > 0) ? 64u  : 0u;  m |= (x1.w > 0) ? 128u : 0u;
    bytes[t] = (uint8_t)m;

    if (blockIdx.x < 64) {
        int idx = blockIdx.x * 256 + threadIdx.x;
        int k = idx >> 7, f = idx & 127;
        WTg[f * 128 + k] = f2bf(W[k * 128 + f]);
    }
}

// ---------------------------------------------------------------------------
// Kernel 1: Wh = h @ W; epilogue: s1/s2 and whT chunk-tiled [b][jc][f][jo].
// XCD-LOCALITY SWIZZLE: b = blockIdx & 7, so XCD x (round-robin dispatch)
// writes only whT[b=x] (512 KB) -- same XCD that attn will read it on.
// Grid 1024 x 256 thr; wave w = 16 rows x 32 f. B-frags straight from WTg.
// ---------------------------------------------------------------------------
__global__ __launch_bounds__(256) void wh_kernel(
        const float* __restrict__ h, const short* __restrict__ WTg,
        const float* __restrict__ a, short* __restrict__ whT,
        float* __restrict__ s1g, float* __restrict__ s2g) {
    __shared__ float sred[4][2][16];
    __shared__ short tr[4][32][24];

    int tid = threadIdx.x, wid = tid >> 6, lane = tid & 63;
    int q = lane >> 4, n = lane & 15;
    int bb = blockIdx.x & 7;                           // XCD-local batch
    int tile = blockIdx.x >> 3;                        // 0..127
    int rb = bb * 2048 + tile * 16;                    // global row base
    int row = rb + n;

    f32x4 acc[2] = {};
    #pragma unroll
    for (int kc = 0; kc < 4; ++kc) {
        const float* hp = h + (size_t)row * 128 + kc * 32 + q * 8;
        float4 h0 = reinterpret_cast<const float4*>(hp)[0];
        float4 h1 = reinterpret_cast<const float4*>(hp)[1];
        bf16x8 afrag;
        afrag[0] = f2bf(h0.x); afrag[1] = f2bf(h0.y);
        afrag[2] = f2bf(h0.z); afrag[3] = f2bf(h0.w);
        afrag[4] = f2bf(h1.x); afrag[5] = f2bf(h1.y);
        afrag[6] = f2bf(h1.z); afrag[7] = f2bf(h1.w);
        #pragma unroll
        for (int u = 0; u < 2; ++u) {
            int t = wid * 2 + u;
            bf16x8 bfrag = *reinterpret_cast<const bf16x8*>(
                WTg + (t * 16 + n) * 128 + kc * 32 + q * 8);
            acc[u] = __builtin_amdgcn_mfma_f32_16x16x32_bf16(afrag, bfrag, acc[u], 0, 0, 0);
        }
    }

    float p1[4] = {0.f, 0.f, 0.f, 0.f}, p2[4] = {0.f, 0.f, 0.f, 0.f};
    #pragma unroll
    for (int u = 0; u < 2; ++u) {
        int c = (wid * 2 + u) * 16 + n;
        float a1c = a[c], a2c = a[128 + c];
        #pragma unroll
        for (int r = 0; r < 4; ++r) {
            p1[r] += acc[u][r] * a1c;
            p2[r] += acc[u][r] * a2c;
        }
    }
    #pragma unroll
    for (int d = 1; d < 16; d <<= 1) {
        #pragma unroll
        for (int r = 0; r < 4; ++r) {
            p1[r] += __shfl_xor(p1[r], d);
            p2[r] += __shfl_xor(p2[r], d);
        }
    }
    if (n == 0) {
        #pragma unroll
        for (int r = 0; r < 4; ++r) {
            sred[wid][0][q * 4 + r] = p1[r];
            sred[wid][1][q * 4 + r] = p2[r];
        }
    }

    #pragma unroll
    for (int u = 0; u < 2; ++u)
        #pragma unroll
        for (int r = 0; r < 4; ++r)
            tr[wid][u * 16 + n][q * 4 + r] = f2bf(acc[u][r]);
    __syncthreads();

    if (wid == 0 && lane < 16) {
        float v1 = 0.f, v2 = 0.f;
        #pragma unroll
        for (int v = 0; v < 4; ++v) { v1 += sred[v][0][lane]; v2 += sred[v][1][lane]; }
        s1g[rb + lane] = v1;
        s2g[rb + lane] = v2;
    }

    int jr = rb & 2047;
    int fl = lane & 31, jh = lane >> 5;
    bf16x8 v = *reinterpret_cast<const bf16x8*>(&tr[wid][fl][jh * 8]);
    int f = wid * 32 + fl;
    int jc = jr >> 5, jo = (jr & 31) + jh * 8;
    *reinterpret_cast<bf16x8*>(
        whT + ((size_t)(bb * 64 + jc) * 128 + f) * 32 + jo) = v;
}

// ---------------------------------------------------------------------------
// Kernel 2 (v7): fused masked-softmax attention + PV, software-pipelined,
// chunk-tiled whT, XCD-LOCALITY SWIZZLE: b = blockIdx & 7 so each XCD reads
// only whT[b] (512 KB, L2-resident) instead of all 4 MB thrashing its L2.
// Grid 512 blocks x 256 thr (4 waves, j-split 4x512).
// ---------------------------------------------------------------------------
__global__ __launch_bounds__(256, 2) void attn_kernel(
        const short* __restrict__ whT, const float* __restrict__ s1g,
        const float* __restrict__ s2g, const uint8_t* __restrict__ adjb,
        float* __restrict__ out) {
    __shared__ f32x4 buf[4][8][64];                    // 32 KB combine buffer
    __shared__ float lds_ds[4][2][16];

    int wid = threadIdx.x >> 6, lane = threadIdx.x & 63;
    int q = lane >> 4, n = lane & 15;
    int b  = blockIdx.x & 7;                           // XCD-local batch
    int ib = (blockIdx.x >> 3) * 32;                   // i-tile 0..63
    int rowA = ib + n, rowB = rowA + 16;

    float s1A = s1g[b * 2048 + rowA];
    float s1B = s1g[b * 2048 + rowB];
    const float* s2b = s2g + b * 2048;
    const uint32_t* admA = reinterpret_cast<const uint32_t*>(adjb + (size_t)rowA * 256);
    const uint32_t* admB = reinterpret_cast<const uint32_t*>(adjb + (size_t)rowB * 256);

    int jbase = wid * 512;
    // chunk-tiled whT: element (b, jc, f, jo) at ((b*64+jc)*128+f)*32+jo
    const short* bpn = whT + (size_t)b * 262144 + n * 32 + q * 8;

    f32x4 accA[8] = {}, accB[8] = {};
    float dsA = 0.f, dsB = 0.f;

    // double-buffered prefetch registers (64 VGPRs for nb — must not spill)
    bf16x8 nb[2][8];
    uint32_t mwA[2], mwB[2];
    float4 s2l[2], s2h[2];

    {   // prologue: chunk 0
        int k0 = jbase;
        mwA[0] = admA[k0 >> 5];
        mwB[0] = admB[k0 >> 5];
        s2l[0] = *reinterpret_cast<const float4*>(s2b + k0 + q * 8);
        s2h[0] = *reinterpret_cast<const float4*>(s2b + k0 + q * 8 + 4);
        const short* bp = bpn + (size_t)(k0 >> 5) * 4096;
        #pragma unroll
        for (int t = 0; t < 8; ++t)
            nb[0][t] = *reinterpret_cast<const bf16x8*>(bp + t * 512);
    }

    #pragma unroll
    for (int c = 0; c < 16; ++c) {
        const int cur = c & 1, nxt = cur ^ 1;
        int k1 = jbase + ((c + 1) & 15) * 32;
        // ---- issue chunk c+1 loads (stay in flight through this chunk)
        mwA[nxt] = admA[k1 >> 5];
        mwB[nxt] = admB[k1 >> 5];
        s2l[nxt] = *reinterpret_cast<const float4*>(s2b + k1 + q * 8);
        s2h[nxt] = *reinterpret_cast<const float4*>(s2b + k1 + q * 8 + 4);
        const short* bp = bpn + (size_t)(k1 >> 5) * 4096;
        #pragma unroll
        for (int t = 0; t < 8; ++t)
            nb[nxt][t] = *reinterpret_cast<const bf16x8*>(bp + t * 512);

        // ---- compute P for chunk c
        uint32_t mA = mwA[cur] >> (q * 8);
        uint32_t mB = mwB[cur] >> (q * 8);
        float s2arr[8] = {s2l[cur].x, s2l[cur].y, s2l[cur].z, s2l[cur].w,
                          s2h[cur].x, s2h[cur].y, s2h[cur].z, s2h[cur].w};
        float pA[8], pB[8];
        #pragma unroll
        for (int j = 0; j < 8; ++j) {
            float eA = s1A + s2arr[j];
            eA = fmaxf(eA, ALPHA * eA);
            float vA = ((mA >> j) & 1) ? __expf(eA) : 0.0f;
            dsA += vA; pA[j] = vA;
            float eB = s1B + s2arr[j];
            eB = fmaxf(eB, ALPHA * eB);
            float vB = ((mB >> j) & 1) ? __expf(eB) : 0.0f;
            dsB += vB; pB[j] = vB;
        }
        union { uint32_t u[4]; bf16x8 v; } cvA, cvB;
        #pragma unroll
        for (int p = 0; p < 4; ++p) {
            cvA.u[p] = pk_bf16(pA[2 * p], pA[2 * p + 1]);
            cvB.u[p] = pk_bf16(pB[2 * p], pB[2 * p + 1]);
        }

        #pragma unroll
        for (int t = 0; t < 8; ++t) {
            accA[t] = __builtin_amdgcn_mfma_f32_16x16x32_bf16(cvA.v, nb[cur][t], accA[t], 0, 0, 0);
            accB[t] = __builtin_amdgcn_mfma_f32_16x16x32_bf16(cvB.v, nb[cur][t], accB[t], 0, 0, 0);
        }
    }

    // ---- denominators (row m in lanes m, m+16, m+32, m+48)
    dsA += __shfl_xor(dsA, 16); dsA += __shfl_xor(dsA, 32);
    dsB += __shfl_xor(dsB, 16); dsB += __shfl_xor(dsB, 32);
    if (q == 0) { lds_ds[wid][0][n] = dsA; lds_ds[wid][1][n] = dsB; }

    // ---- combine round A
    #pragma unroll
    for (int i = 0; i < 8; ++i) buf[wid][i][lane] = accA[i];
    __syncthreads();

    int t0 = wid * 2, t1 = wid * 2 + 1;
    f32x4 rA0 = buf[0][t0][lane] + buf[1][t0][lane] + buf[2][t0][lane] + buf[3][t0][lane];
    f32x4 rA1 = buf[0][t1][lane] + buf[1][t1][lane] + buf[2][t1][lane] + buf[3][t1][lane];

    float dAt = lds_ds[0][0][n] + lds_ds[1][0][n] + lds_ds[2][0][n] + lds_ds[3][0][n];
    float dBt = lds_ds[0][1][n] + lds_ds[1][1][n] + lds_ds[2][1][n] + lds_ds[3][1][n];
    float rdA[4], rdB[4];
    #pragma unroll
    for (int r = 0; r < 4; ++r) {
        rdA[r] = 1.0f / __shfl(dAt, q * 4 + r);
        rdB[r] = 1.0f / __shfl(dBt, q * 4 + r);
    }

    size_t ob = ((size_t)b * 2048 + ib) * 128;
    #pragma unroll
    for (int r = 0; r < 4; ++r) {
        out[ob + (size_t)(q * 4 + r) * 128 + t0 * 16 + n] = rA0[r] * rdA[r];
        out[ob + (size_t)(q * 4 + r) * 128 + t1 * 16 + n] = rA1[r] * rdA[r];
    }
    __syncthreads();

    // ---- combine round B
    #pragma unroll
    for (int i = 0; i < 8; ++i) buf[wid][i][lane] = accB[i];
    __syncthreads();

    f32x4 rB0 = buf[0][t0][lane] + buf[1][t0][lane] + buf[2][t0][lane] + buf[3][t0][lane];
    f32x4 rB1 = buf[0][t1][lane] + buf[1][t1][lane] + buf[2][t1][lane] + buf[3][t1][lane];
    #pragma unroll
    for (int r = 0; r < 4; ++r) {
        out[ob + (size_t)(16 + q * 4 + r) * 128 + t0 * 16 + n] = rB0[r] * rdB[r];
        out[ob + (size_t)(16 + q * 4 + r) * 128 + t1 * 16 + n] = rB1[r] * rdB[r];
    }
}

// ---------------------------------------------------------------------------
extern "C" void kernel_launch(void* const* d_in, const int* in_sizes, int n_in,
                              void* d_out, int out_size, void* d_ws, size_t ws_size,
                              hipStream_t stream) {
    const float* h   = (const float*)d_in[0];   // [8][2048][128] f32
    const int*   adj = (const int*)d_in[1];     // [2048][2048] i32
    const float* W   = (const float*)d_in[2];   // [128][128] f32
    const float* a   = (const float*)d_in[3];   // [256][1] f32
    float* out = (float*)d_out;                 // [8][2048][128] f32

    char* ws = (char*)d_ws;
    short* whT = (short*)ws;                                  // 4 MB  bf16 whT (chunk-tiled)
    float* s1  = (float*)(ws + 4194304);                      // 64 KB
    float* s2  = (float*)(ws + 4259840);                      // 64 KB
    uint8_t* bytes = (uint8_t*)(ws + 4325376);                // 512 KB

    // WT scratch in the tail of d_out (32 KB); wh reads it before attn
    // overwrites d_out. Same-stream ordering makes this safe.
    short* WTg = (short*)d_out + (4194304 - 16384);

    pack_adj_kernel<<<2048, 256, 0, stream>>>(adj, bytes, W, WTg);
    wh_kernel<<<1024, 256, 0, stream>>>(h, WTg, a, whT, s1, s2);
    attn_kernel<<<512, 256, 0, stream>>>(whT, s1, s2, bytes, out);
}

// Round 8
// 111.674 us; speedup vs baseline: 1.0305x; 1.0305x over previous
//
#include <hip/hip_runtime.h>
#include <hip/hip_bf16.h>
#include <stdint.h>

#define ALPHA 0.2f

typedef __attribute__((ext_vector_type(8))) short bf16x8;
typedef __attribute__((ext_vector_type(4))) float f32x4;

__device__ __forceinline__ short f2bf(float f) {
    union { float f; uint32_t u; } c; c.f = f;
    uint32_t u = c.u + 0x7FFF + ((c.u >> 16) & 1);   // round-to-nearest-even
    return (short)(u >> 16);
}

// pack two fp32 -> packed bf16 pair (round-half-up), 3 VALU ops for 2 elems
__device__ __forceinline__ uint32_t pk_bf16(float lo, float hi) {
    union { float f; uint32_t u; } a, b;
    a.f = lo; b.f = hi;
    return __builtin_amdgcn_perm(b.u + 0x8000u, a.u + 0x8000u, 0x07060302u);
}

// ---------------------------------------------------------------------------
// Kernel 0: pack adj into byte-masks (8 ints -> 1 byte per thread). First 64
// blocks also pre-transpose W (fp32 [k][f]) -> WTg (bf16 [f][k]).
// ---------------------------------------------------------------------------
__global__ __launch_bounds__(256) void pack_adj_kernel(
        const int* __restrict__ adj, uint8_t* __restrict__ bytes,
        const float* __restrict__ W, short* __restrict__ WTg) {
    int t = blockIdx.x * 256 + threadIdx.x;            // 524288 threads
    const int4* a4 = reinterpret_cast<const int4*>(adj) + (size_t)t * 2;
    int4 x0 = a4[0], x1 = a4[1];
    uint32_t m = 0;
    m |= (x0.x > 0) ? 1u   : 0u;  m |= (x0.y > 0) ? 2u   : 0u;
    m |= (x0.z > 0) ? 4u   : 0u;  m |= (x0.w > 0) ? 8u   : 0u;
    m |= (x1.x > 0) ? 16u  : 0u;  m |= (x1.y > 0) ? 32u  : 0u;
    m |= (x1.z > 0) ? 64u  : 0u;  m |= (x1.w > 0) ? 128u : 0u;
    bytes[t] = (uint8_t)m;

    if (blockIdx.x < 64) {
        int idx = blockIdx.x * 256 + threadIdx.x;
        int k = idx >> 7, f = idx & 127;
        WTg[f * 128 + k] = f2bf(W[k * 128 + f]);
    }
}

// ---------------------------------------------------------------------------
// Kernel 1: Wh = h @ W; epilogue: s1/s2 and whT chunk-tiled [b][jc][f][jo].
// XCD swizzle: b = blockIdx & 7. Grid 1024 x 256 thr.
// ---------------------------------------------------------------------------
__global__ __launch_bounds__(256) void wh_kernel(
        const float* __restrict__ h, const short* __restrict__ WTg,
        const float* __restrict__ a, short* __restrict__ whT,
        float* __restrict__ s1g, float* __restrict__ s2g) {
    __shared__ float sred[4][2][16];
    __shared__ short tr[4][32][24];

    int tid = threadIdx.x, wid = tid >> 6, lane = tid & 63;
    int q = lane >> 4, n = lane & 15;
    int bb = blockIdx.x & 7;                           // XCD-local batch
    int tile = blockIdx.x >> 3;                        // 0..127
    int rb = bb * 2048 + tile * 16;                    // global row base
    int row = rb + n;

    f32x4 acc[2] = {};
    #pragma unroll
    for (int kc = 0; kc < 4; ++kc) {
        const float* hp = h + (size_t)row * 128 + kc * 32 + q * 8;
        float4 h0 = reinterpret_cast<const float4*>(hp)[0];
        float4 h1 = reinterpret_cast<const float4*>(hp)[1];
        bf16x8 afrag;
        afrag[0] = f2bf(h0.x); afrag[1] = f2bf(h0.y);
        afrag[2] = f2bf(h0.z); afrag[3] = f2bf(h0.w);
        afrag[4] = f2bf(h1.x); afrag[5] = f2bf(h1.y);
        afrag[6] = f2bf(h1.z); afrag[7] = f2bf(h1.w);
        #pragma unroll
        for (int u = 0; u < 2; ++u) {
            int t = wid * 2 + u;
            bf16x8 bfrag = *reinterpret_cast<const bf16x8*>(
                WTg + (t * 16 + n) * 128 + kc * 32 + q * 8);
            acc[u] = __builtin_amdgcn_mfma_f32_16x16x32_bf16(afrag, bfrag, acc[u], 0, 0, 0);
        }
    }

    float p1[4] = {0.f, 0.f, 0.f, 0.f}, p2[4] = {0.f, 0.f, 0.f, 0.f};
    #pragma unroll
    for (int u = 0; u < 2; ++u) {
        int c = (wid * 2 + u) * 16 + n;
        float a1c = a[c], a2c = a[128 + c];
        #pragma unroll
        for (int r = 0; r < 4; ++r) {
            p1[r] += acc[u][r] * a1c;
            p2[r] += acc[u][r] * a2c;
        }
    }
    #pragma unroll
    for (int d = 1; d < 16; d <<= 1) {
        #pragma unroll
        for (int r = 0; r < 4; ++r) {
            p1[r] += __shfl_xor(p1[r], d);
            p2[r] += __shfl_xor(p2[r], d);
        }
    }
    if (n == 0) {
        #pragma unroll
        for (int r = 0; r < 4; ++r) {
            sred[wid][0][q * 4 + r] = p1[r];
            sred[wid][1][q * 4 + r] = p2[r];
        }
    }

    #pragma unroll
    for (int u = 0; u < 2; ++u)
        #pragma unroll
        for (int r = 0; r < 4; ++r)
            tr[wid][u * 16 + n][q * 4 + r] = f2bf(acc[u][r]);
    __syncthreads();

    if (wid == 0 && lane < 16) {
        float v1 = 0.f, v2 = 0.f;
        #pragma unroll
        for (int v = 0; v < 4; ++v) { v1 += sred[v][0][lane]; v2 += sred[v][1][lane]; }
        s1g[rb + lane] = v1;
        s2g[rb + lane] = v2;
    }

    int jr = rb & 2047;
    int fl = lane & 31, jh = lane >> 5;
    bf16x8 v = *reinterpret_cast<const bf16x8*>(&tr[wid][fl][jh * 8]);
    int f = wid * 32 + fl;
    int jc = jr >> 5, jo = (jr & 31) + jh * 8;
    *reinterpret_cast<bf16x8*>(
        whT + ((size_t)(bb * 64 + jc) * 128 + f) * 32 + jo) = v;
}

// ---------------------------------------------------------------------------
// Kernel 2 (v8): fused masked-softmax attention + PV.
// v7 + MASK HOIST: each wave pre-loads its whole 512-j mask slice for all 32
// rows (2 uint4 loads/wave, replacing 32 scattered per-chunk loads) and
// distributes per-chunk dwords via __shfl (DS pipe, no memory dependence).
// Grid 512 blocks x 256 thr (4 waves, j-split 4x512), chunk-tiled whT,
// XCD swizzle, register double-buffered B prefetch.
// ---------------------------------------------------------------------------
__global__ __launch_bounds__(256, 2) void attn_kernel(
        const short* __restrict__ whT, const float* __restrict__ s1g,
        const float* __restrict__ s2g, const uint8_t* __restrict__ adjb,
        float* __restrict__ out) {
    __shared__ f32x4 buf[4][8][64];                    // 32 KB combine buffer
    __shared__ float lds_ds[4][2][16];

    int wid = threadIdx.x >> 6, lane = threadIdx.x & 63;
    int q = lane >> 4, n = lane & 15;
    int b  = blockIdx.x & 7;                           // XCD-local batch
    int ib = (blockIdx.x >> 3) * 32;                   // i-tile 0..63
    int rowA = ib + n, rowB = rowA + 16;

    float s1A = s1g[b * 2048 + rowA];
    float s1B = s1g[b * 2048 + rowB];
    const float* s2b = s2g + b * 2048;

    int jbase = wid * 512;

    // ---- mask hoist: lane (q,n) holds dwords [q*4 .. q*4+3] of the 16-dword
    // (512-bit) mask slice of row n (set A) / row n+16 (set B).
    uint4 mregA = *reinterpret_cast<const uint4*>(
        adjb + (size_t)rowA * 256 + wid * 64 + q * 16);
    uint4 mregB = *reinterpret_cast<const uint4*>(
        adjb + (size_t)rowB * 256 + wid * 64 + q * 16);
    const uint32_t* mrA = reinterpret_cast<const uint32_t*>(&mregA);
    const uint32_t* mrB = reinterpret_cast<const uint32_t*>(&mregB);

    // chunk-tiled whT: element (b, jc, f, jo) at ((b*64+jc)*128+f)*32+jo
    const short* bpn = whT + (size_t)b * 262144 + n * 32 + q * 8;

    f32x4 accA[8] = {}, accB[8] = {};
    float dsA = 0.f, dsB = 0.f;

    // double-buffered prefetch registers (64 VGPRs for nb — must not spill)
    bf16x8 nb[2][8];
    float4 s2l[2], s2h[2];

    {   // prologue: chunk 0
        int k0 = jbase;
        s2l[0] = *reinterpret_cast<const float4*>(s2b + k0 + q * 8);
        s2h[0] = *reinterpret_cast<const float4*>(s2b + k0 + q * 8 + 4);
        const short* bp = bpn + (size_t)(k0 >> 5) * 4096;
        #pragma unroll
        for (int t = 0; t < 8; ++t)
            nb[0][t] = *reinterpret_cast<const bf16x8*>(bp + t * 512);
    }

    #pragma unroll
    for (int c = 0; c < 16; ++c) {
        const int cur = c & 1, nxt = cur ^ 1;
        int k1 = jbase + ((c + 1) & 15) * 32;
        // ---- issue chunk c+1 loads (stay in flight through this chunk)
        s2l[nxt] = *reinterpret_cast<const float4*>(s2b + k1 + q * 8);
        s2h[nxt] = *reinterpret_cast<const float4*>(s2b + k1 + q * 8 + 4);
        const short* bp = bpn + (size_t)(k1 >> 5) * 4096;
        #pragma unroll
        for (int t = 0; t < 8; ++t)
            nb[nxt][t] = *reinterpret_cast<const bf16x8*>(bp + t * 512);

        // ---- mask dword for chunk c via cross-lane shuffle (no memory)
        int srcl = (c >> 2) * 16 + n;                  // lane holding dword c
        uint32_t mAd = (uint32_t)__shfl((int)mrA[c & 3], srcl);
        uint32_t mBd = (uint32_t)__shfl((int)mrB[c & 3], srcl);
        uint32_t mA = mAd >> (q * 8);
        uint32_t mB = mBd >> (q * 8);

        // ---- compute P for chunk c
        float s2arr[8] = {s2l[cur].x, s2l[cur].y, s2l[cur].z, s2l[cur].w,
                          s2h[cur].x, s2h[cur].y, s2h[cur].z, s2h[cur].w};
        float pA[8], pB[8];
        #pragma unroll
        for (int j = 0; j < 8; ++j) {
            float eA = s1A + s2arr[j];
            eA = fmaxf(eA, ALPHA * eA);
            float vA = ((mA >> j) & 1) ? __expf(eA) : 0.0f;
            dsA += vA; pA[j] = vA;
            float eB = s1B + s2arr[j];
            eB = fmaxf(eB, ALPHA * eB);
            float vB = ((mB >> j) & 1) ? __expf(eB) : 0.0f;
            dsB += vB; pB[j] = vB;
        }
        union { uint32_t u[4]; bf16x8 v; } cvA, cvB;
        #pragma unroll
        for (int p = 0; p < 4; ++p) {
            cvA.u[p] = pk_bf16(pA[2 * p], pA[2 * p + 1]);
            cvB.u[p] = pk_bf16(pB[2 * p], pB[2 * p + 1]);
        }

        #pragma unroll
        for (int t = 0; t < 8; ++t) {
            accA[t] = __builtin_amdgcn_mfma_f32_16x16x32_bf16(cvA.v, nb[cur][t], accA[t], 0, 0, 0);
            accB[t] = __builtin_amdgcn_mfma_f32_16x16x32_bf16(cvB.v, nb[cur][t], accB[t], 0, 0, 0);
        }
    }

    // ---- denominators (row m in lanes m, m+16, m+32, m+48)
    dsA += __shfl_xor(dsA, 16); dsA += __shfl_xor(dsA, 32);
    dsB += __shfl_xor(dsB, 16); dsB += __shfl_xor(dsB, 32);
    if (q == 0) { lds_ds[wid][0][n] = dsA; lds_ds[wid][1][n] = dsB; }

    // ---- combine round A
    #pragma unroll
    for (int i = 0; i < 8; ++i) buf[wid][i][lane] = accA[i];
    __syncthreads();

    int t0 = wid * 2, t1 = wid * 2 + 1;
    f32x4 rA0 = buf[0][t0][lane] + buf[1][t0][lane] + buf[2][t0][lane] + buf[3][t0][lane];
    f32x4 rA1 = buf[0][t1][lane] + buf[1][t1][lane] + buf[2][t1][lane] + buf[3][t1][lane];

    float dAt = lds_ds[0][0][n] + lds_ds[1][0][n] + lds_ds[2][0][n] + lds_ds[3][0][n];
    float dBt = lds_ds[0][1][n] + lds_ds[1][1][n] + lds_ds[2][1][n] + lds_ds[3][1][n];
    float rdA[4], rdB[4];
    #pragma unroll
    for (int r = 0; r < 4; ++r) {
        rdA[r] = 1.0f / __shfl(dAt, q * 4 + r);
        rdB[r] = 1.0f / __shfl(dBt, q * 4 + r);
    }

    size_t ob = ((size_t)b * 2048 + ib) * 128;
    #pragma unroll
    for (int r = 0; r < 4; ++r) {
        out[ob + (size_t)(q * 4 + r) * 128 + t0 * 16 + n] = rA0[r] * rdA[r];
        out[ob + (size_t)(q * 4 + r) * 128 + t1 * 16 + n] = rA1[r] * rdA[r];
    }
    __syncthreads();

    // ---- combine round B
    #pragma unroll
    for (int i = 0; i < 8; ++i) buf[wid][i][lane] = accB[i];
    __syncthreads();

    f32x4 rB0 = buf[0][t0][lane] + buf[1][t0][lane] + buf[2][t0][lane] + buf[3][t0][lane];
    f32x4 rB1 = buf[0][t1][lane] + buf[1][t1][lane] + buf[2][t1][lane] + buf[3][t1][lane];
    #pragma unroll
    for (int r = 0; r < 4; ++r) {
        out[ob + (size_t)(16 + q * 4 + r) * 128 + t0 * 16 + n] = rB0[r] * rdB[r];
        out[ob + (size_t)(16 + q * 4 + r) * 128 + t1 * 16 + n] = rB1[r] * rdB[r];
    }
}

// ---------------------------------------------------------------------------
extern "C" void kernel_launch(void* const* d_in, const int* in_sizes, int n_in,
                              void* d_out, int out_size, void* d_ws, size_t ws_size,
                              hipStream_t stream) {
    const float* h   = (const float*)d_in[0];   // [8][2048][128] f32
    const int*   adj = (const int*)d_in[1];     // [2048][2048] i32
    const float* W   = (const float*)d_in[2];   // [128][128] f32
    const float* a   = (const float*)d_in[3];   // [256][1] f32
    float* out = (float*)d_out;                 // [8][2048][128] f32

    char* ws = (char*)d_ws;
    short* whT = (short*)ws;                                  // 4 MB  bf16 whT (chunk-tiled)
    float* s1  = (float*)(ws + 4194304);                      // 64 KB
    float* s2  = (float*)(ws + 4259840);                      // 64 KB
    uint8_t* bytes = (uint8_t*)(ws + 4325376);                // 512 KB

    // WT scratch in the tail of d_out (32 KB); wh reads it before attn
    // overwrites d_out. Same-stream ordering makes this safe.
    short* WTg = (short*)d_out + (4194304 - 16384);

    pack_adj_kernel<<<2048, 256, 0, stream>>>(adj, bytes, W, WTg);
    wh_kernel<<<1024, 256, 0, stream>>>(h, WTg, a, whT, s1, s2);
    attn_kernel<<<512, 256, 0, stream>>>(whT, s1, s2, bytes, out);
}